// Round 1
// baseline (544.815 us; speedup 1.0000x reference)
//
#include <hip/hip_runtime.h>

// DEC soft assignment: q = rownorm(1/(1 + ||x-c||^2)), ALPHA=1 so power term is identity.
// bf16 MFMA for x.c^T (error budget: dq ~ 2e-7 << 4e-5 threshold); fp32 x^2/c^2/normalize.
// R2: MT 32->64, wave tile 64x128.
// R3: restructure to barrier-free K-loop.
//     - Stage the ENTIRE 64x512 bf16 A tile in LDS once (one barrier total).
//     - B (centers, 512KB bf16) is L2-resident: read MFMA B-fragments directly from
//       global (16B/lane dwordx4, immediate offsets) -- no B LDS, no per-step barriers,
//       no vmcnt(0) drains. Waves pipeline independently (m114 implicit-overlap regime).
//     - A row stride 520 shorts (1040B): uniform 8-slot b128 bank distribution.

typedef __attribute__((ext_vector_type(8))) short short8_t;
typedef __attribute__((ext_vector_type(4))) short short4_t;
typedef __attribute__((ext_vector_type(4))) float f32x4;

#define NROWS 131072
#define DDIM  512
#define NCL   512
#define MT    64
#define LDA   520   // shorts; 1040B row stride -> bandwidth-optimal b128 bank spread

__device__ __forceinline__ unsigned short f2bf(float f) {
    unsigned u = __float_as_uint(f);
    u += 0x7FFFu + ((u >> 16) & 1u);
    return (unsigned short)(u >> 16);
}

// ---- prep: convert centers to bf16, compute ||c_k||^2 in fp32 ----
__global__ __launch_bounds__(128) void prep_centers(
        const float* __restrict__ c, unsigned short* __restrict__ cb,
        float* __restrict__ c2) {
    const int k = blockIdx.x, t = threadIdx.x;
    float4 v = ((const float4*)(c + k * DDIM))[t];
    float ss = v.x * v.x + v.y * v.y + v.z * v.z + v.w * v.w;
    short4_t s;
    s.x = (short)f2bf(v.x); s.y = (short)f2bf(v.y);
    s.z = (short)f2bf(v.z); s.w = (short)f2bf(v.w);
    ((short4_t*)(cb + k * DDIM))[t] = s;
#pragma unroll
    for (int off = 32; off >= 1; off >>= 1) ss += __shfl_xor(ss, off, 64);
    __shared__ float red[2];
    if ((t & 63) == 0) red[t >> 6] = ss;
    __syncthreads();
    if (t == 0) c2[k] = red[0] + red[1];
}

// ---- main: 64 rows x 512 clusters per block, 256 threads = 4 waves (each 64x128) ----
__global__ __launch_bounds__(256, 2) void dec_soft_assign(
        const float* __restrict__ x, const unsigned short* __restrict__ cb,
        const float* __restrict__ c2g, float* __restrict__ out) {
    __shared__ __align__(16) unsigned short Alds[MT * LDA];   // 66.56 KB
    __shared__ float x2_lds[MT];
    __shared__ float rs_lds[MT][4];
    __shared__ float inv_lds[MT];

    const int t   = threadIdx.x;
    const int w   = t >> 6;        // wave 0..3
    const int l   = t & 63;
    const int q   = l >> 4;        // quad (k-chunk selector for fragments)
    const int l15 = l & 15;
    const int m0  = blockIdx.x * MT;

    // ---- stage full A tile (64 rows x 512 k) fp32 -> bf16, accumulate ||x||^2 ----
    // thread t owns row ar = t>>2, 8-elem k-chunk (t&3) of each 32-k group
    const int ar  = t >> 2;        // 0..63
    const int acj = t & 3;         // 0..3
    const float4* xp = (const float4*)(x + (long)(m0 + ar) * DDIM) + acj * 2;
    unsigned short* aw = &Alds[ar * LDA + acj * 8];

    float x2a = 0.f;
#pragma unroll 4
    for (int kt = 0; kt < 16; ++kt) {
        float4 v0 = xp[kt * 8], v1 = xp[kt * 8 + 1];
        x2a += v0.x * v0.x + v0.y * v0.y + v0.z * v0.z + v0.w * v0.w;
        x2a += v1.x * v1.x + v1.y * v1.y + v1.z * v1.z + v1.w * v1.w;
        short8_t a8;
        a8[0] = (short)f2bf(v0.x); a8[1] = (short)f2bf(v0.y);
        a8[2] = (short)f2bf(v0.z); a8[3] = (short)f2bf(v0.w);
        a8[4] = (short)f2bf(v1.x); a8[5] = (short)f2bf(v1.y);
        a8[6] = (short)f2bf(v1.z); a8[7] = (short)f2bf(v1.w);
        *(short8_t*)(aw + kt * 32) = a8;
    }
    // reduce ||x||^2 over the 4 staging lanes of each row
    x2a += __shfl_xor(x2a, 1, 64);
    x2a += __shfl_xor(x2a, 2, 64);
    if (acj == 0) x2_lds[ar] = x2a;

    // ---- B fragment pointers: column n = w*128 + nt*16 + l15, k-offset q*8 ----
    const unsigned short* pB[8];
#pragma unroll
    for (int nt = 0; nt < 8; ++nt)
        pB[nt] = cb + (long)(w * 128 + nt * 16 + l15) * DDIM + q * 8;

    const unsigned short* pA = &Alds[l15 * LDA + q * 8];

    f32x4 acc[4][8];
#pragma unroll
    for (int mt = 0; mt < 4; ++mt)
#pragma unroll
        for (int nt = 0; nt < 8; ++nt)
            acc[mt][nt] = (f32x4){0.f, 0.f, 0.f, 0.f};

    __syncthreads();               // A tile + x2 visible; the ONLY pre-epilogue barrier

    // ---- main K loop: no barriers. A from LDS, B from L2, all immediate offsets ----
#pragma unroll
    for (int kt = 0; kt < 16; ++kt) {
        short8_t bfr[8];
#pragma unroll
        for (int nt = 0; nt < 8; ++nt)
            bfr[nt] = *(const short8_t*)(pB[nt] + kt * 32);
        short8_t afr[4];
#pragma unroll
        for (int mt = 0; mt < 4; ++mt)
            afr[mt] = *(const short8_t*)(pA + mt * 16 * LDA + kt * 32);
#pragma unroll
        for (int nt = 0; nt < 8; ++nt)
#pragma unroll
            for (int mt = 0; mt < 4; ++mt)
                acc[mt][nt] = __builtin_amdgcn_mfma_f32_16x16x32_bf16(afr[mt], bfr[nt], acc[mt][nt], 0, 0, 0);
    }

    // ---- epilogue: dist2 -> clamp -> 1/(1+d), row sums ----
    float c2v[8];
#pragma unroll
    for (int nt = 0; nt < 8; ++nt)
        c2v[nt] = c2g[w * 128 + nt * 16 + l15];

    float rsum[4][4];
#pragma unroll
    for (int mt = 0; mt < 4; ++mt)
#pragma unroll
        for (int r = 0; r < 4; ++r) rsum[mt][r] = 0.f;

#pragma unroll
    for (int mt = 0; mt < 4; ++mt) {
#pragma unroll
        for (int r = 0; r < 4; ++r) {
            float xv = x2_lds[mt * 16 + q * 4 + r];
#pragma unroll
            for (int nt = 0; nt < 8; ++nt) {
                float d = xv + c2v[nt] - 2.0f * acc[mt][nt][r];
                d = fmaxf(d, 0.0f);
                float qq = __builtin_amdgcn_rcpf(1.0f + d);
                acc[mt][nt][r] = qq;         // reuse acc registers for q
                rsum[mt][r] += qq;
            }
        }
    }
    // reduce row partials across 16 lanes sharing a row, then across 4 waves via LDS
#pragma unroll
    for (int mt = 0; mt < 4; ++mt)
#pragma unroll
        for (int r = 0; r < 4; ++r) {
            float s = rsum[mt][r];
            s += __shfl_xor(s, 1, 64);
            s += __shfl_xor(s, 2, 64);
            s += __shfl_xor(s, 4, 64);
            s += __shfl_xor(s, 8, 64);
            if (l15 == 0) rs_lds[mt * 16 + q * 4 + r][w] = s;
        }
    __syncthreads();
    if (t < MT) {
        float s = rs_lds[t][0] + rs_lds[t][1] + rs_lds[t][2] + rs_lds[t][3];
        inv_lds[t] = __builtin_amdgcn_rcpf(s);
    }
    __syncthreads();

    // ---- store normalized q (coalesced: 16 consecutive floats per quad) ----
#pragma unroll
    for (int mt = 0; mt < 4; ++mt)
#pragma unroll
        for (int r = 0; r < 4; ++r) {
            int row = mt * 16 + q * 4 + r;
            float inv = inv_lds[row];
            float* orow = out + (long)(m0 + row) * NCL + w * 128;
#pragma unroll
            for (int nt = 0; nt < 8; ++nt)
                orow[nt * 16 + l15] = acc[mt][nt][r] * inv;
        }
}

extern "C" void kernel_launch(void* const* d_in, const int* in_sizes, int n_in,
                              void* d_out, int out_size, void* d_ws, size_t ws_size,
                              hipStream_t stream) {
    const float* x       = (const float*)d_in[0];
    const float* centers = (const float*)d_in[1];
    float* out           = (float*)d_out;

    unsigned short* cb = (unsigned short*)d_ws;                         // 512*512 bf16 = 512 KB
    float* c2          = (float*)((char*)d_ws + NCL * DDIM * sizeof(unsigned short)); // 2 KB

    prep_centers<<<NCL, 128, 0, stream>>>(centers, cb, c2);
    dec_soft_assign<<<NROWS / MT, 256, 0, stream>>>(x, cb, c2, out);
}